// Round 2
// baseline (1308.504 us; speedup 1.0000x reference)
//
#include <hip/hip_runtime.h>

#define N_NODES 50000
#define E_EDGES 600000
#define IN_DIM  128
#define HID     256
#define OUT_DIM 128
#define M_TILE  32
#define SM_PAD  36   // LDS row stride (floats): %4==0 keeps float4 16B-aligned, spreads banks

// ---------------------------------------------------------------------------
// Kernel 1: zero workspace (msg accumulator + degree). ws is poisoned 0xAA
// before every launch.
// ---------------------------------------------------------------------------
__global__ void sage_zero(float* __restrict__ msg, int* __restrict__ deg) {
    int stride = gridDim.x * blockDim.x;
    int i = blockIdx.x * blockDim.x + threadIdx.x;
    const int total = N_NODES * IN_DIM;
    for (int j = i; j < total; j += stride) msg[j] = 0.0f;
    for (int j = i; j < N_NODES; j += stride) deg[j] = 0;
}

// ---------------------------------------------------------------------------
// Kernel 2: scatter-add messages. 32 threads/edge, float4 per thread.
// unsafeAtomicAdd -> native global_atomic_add_f32 (no CAS loop).
// ---------------------------------------------------------------------------
__global__ void sage_scatter(const float* __restrict__ h,
                             const int* __restrict__ src,
                             const int* __restrict__ dst,
                             float* __restrict__ msg,
                             int* __restrict__ deg) {
    int gid = blockIdx.x * blockDim.x + threadIdx.x;
    int e = gid >> 5;
    int lane = gid & 31;
    if (e >= E_EDGES) return;

    int s = src[e];
    int d = dst[e];

    const float4 hv = *(const float4*)(h + (size_t)s * IN_DIM + lane * 4);
    float* mp = msg + (size_t)d * IN_DIM + lane * 4;

    unsafeAtomicAdd(mp + 0, hv.x);
    unsafeAtomicAdd(mp + 1, hv.y);
    unsafeAtomicAdd(mp + 2, hv.z);
    unsafeAtomicAdd(mp + 3, hv.w);

    if (lane == 0) atomicAdd(deg + d, 1);
}

// ---------------------------------------------------------------------------
// Kernel 3: fused mean + 2-layer MLP + relu, register-tiled fp32 GEMM.
// One block = 256 threads = 32 nodes.
//   sm[k][m] : transposed input tile (k = 0..255 feature, m = node in tile),
//              reused for the transposed hidden tile between layers.
// Layer 1: thread (i=t>>5, j=t&31) computes rows i*4..i*4+3, cols j*8..j*8+7.
// Layer 2: thread (i,j) computes rows i*4..i*4+3, cols j*4..j*4+3.
// Weights are read straight from global (hot in L2: W1+W2 = 384 KB fp32).
// ---------------------------------------------------------------------------
__global__ void __launch_bounds__(256)
sage_mlp(const float* __restrict__ h,
         const float* __restrict__ msg,
         const int* __restrict__ deg,
         const float* __restrict__ W1,
         const float* __restrict__ b1,
         const float* __restrict__ W2,
         const float* __restrict__ b2,
         float* __restrict__ out) {
    __shared__ float sm[2 * IN_DIM][SM_PAD];   // 256 x 36 floats = 36 KB

    const int t = threadIdx.x;
    const int base = blockIdx.x * M_TILE;
    const int i = t >> 5;   // 0..7  -> 4-row group
    const int j = t & 31;   // 0..31 -> col group

    // ---- load + mean: sm[t][m] = h_total[base+m][t] -------------------------
    for (int m = 0; m < M_TILE; ++m) {
        int n = base + m;
        float v = 0.0f;
        if (n < N_NODES) {
            if (t < IN_DIM) {
                v = h[(size_t)n * IN_DIM + t];
            } else {
                float dg = (float)max(deg[n], 1);
                v = msg[(size_t)n * IN_DIM + (t - IN_DIM)] / dg;
            }
        }
        sm[t][m] = v;
    }
    __syncthreads();

    // ---- layer 1: hid[m][c] = b1[c] + sum_k ht[m][k] * W1[k][c] ------------
    float acc1[4][8];
    {
        const float4 bv0 = *(const float4*)(b1 + j * 8);
        const float4 bv1 = *(const float4*)(b1 + j * 8 + 4);
        #pragma unroll
        for (int mm = 0; mm < 4; ++mm) {
            acc1[mm][0] = bv0.x; acc1[mm][1] = bv0.y; acc1[mm][2] = bv0.z; acc1[mm][3] = bv0.w;
            acc1[mm][4] = bv1.x; acc1[mm][5] = bv1.y; acc1[mm][6] = bv1.z; acc1[mm][7] = bv1.w;
        }
    }
    for (int k = 0; k < 2 * IN_DIM; ++k) {
        const float4 a  = *(const float4*)&sm[k][i * 4];
        const float4 w0 = *(const float4*)(W1 + (size_t)k * HID + j * 8);
        const float4 w1 = *(const float4*)(W1 + (size_t)k * HID + j * 8 + 4);
        const float av[4] = {a.x, a.y, a.z, a.w};
        const float wv[8] = {w0.x, w0.y, w0.z, w0.w, w1.x, w1.y, w1.z, w1.w};
        #pragma unroll
        for (int mm = 0; mm < 4; ++mm)
            #pragma unroll
            for (int cc = 0; cc < 8; ++cc)
                acc1[mm][cc] = fmaf(av[mm], wv[cc], acc1[mm][cc]);
    }
    __syncthreads();

    // ---- store hid transposed back into sm: sm[c][m] -----------------------
    #pragma unroll
    for (int cc = 0; cc < 8; ++cc)
        #pragma unroll
        for (int mm = 0; mm < 4; ++mm)
            sm[j * 8 + cc][i * 4 + mm] = acc1[mm][cc];
    __syncthreads();

    // ---- layer 2: out[m][c] = relu(b2[c] + sum_k hid[m][k] * W2[k][c]) -----
    float acc2[4][4];
    {
        const float4 bv = *(const float4*)(b2 + j * 4);
        #pragma unroll
        for (int mm = 0; mm < 4; ++mm) {
            acc2[mm][0] = bv.x; acc2[mm][1] = bv.y; acc2[mm][2] = bv.z; acc2[mm][3] = bv.w;
        }
    }
    for (int k = 0; k < HID; ++k) {
        const float4 a = *(const float4*)&sm[k][i * 4];
        const float4 w = *(const float4*)(W2 + (size_t)k * OUT_DIM + j * 4);
        const float av[4] = {a.x, a.y, a.z, a.w};
        const float wv[4] = {w.x, w.y, w.z, w.w};
        #pragma unroll
        for (int mm = 0; mm < 4; ++mm)
            #pragma unroll
            for (int cc = 0; cc < 4; ++cc)
                acc2[mm][cc] = fmaf(av[mm], wv[cc], acc2[mm][cc]);
    }

    #pragma unroll
    for (int mm = 0; mm < 4; ++mm) {
        int n = base + i * 4 + mm;
        if (n < N_NODES) {
            float4 o;
            o.x = fmaxf(acc2[mm][0], 0.0f);
            o.y = fmaxf(acc2[mm][1], 0.0f);
            o.z = fmaxf(acc2[mm][2], 0.0f);
            o.w = fmaxf(acc2[mm][3], 0.0f);
            *(float4*)(out + (size_t)n * OUT_DIM + j * 4) = o;
        }
    }
}

extern "C" void kernel_launch(void* const* d_in, const int* in_sizes, int n_in,
                              void* d_out, int out_size, void* d_ws, size_t ws_size,
                              hipStream_t stream) {
    const float* h   = (const float*)d_in[0];
    const int*   src = (const int*)d_in[1];
    const int*   dst = (const int*)d_in[2];
    const float* W1  = (const float*)d_in[3];
    const float* b1  = (const float*)d_in[4];
    const float* W2  = (const float*)d_in[5];
    const float* b2  = (const float*)d_in[6];
    float* out = (float*)d_out;

    float* msg = (float*)d_ws;
    int*   deg = (int*)((char*)d_ws + sizeof(float) * (size_t)N_NODES * IN_DIM);

    // 1. clear accumulators
    sage_zero<<<2048, 256, 0, stream>>>(msg, deg);

    // 2. scatter-add messages + degrees
    {
        long long total_threads = (long long)E_EDGES * 32;
        int blocks = (int)((total_threads + 255) / 256);
        sage_scatter<<<blocks, 256, 0, stream>>>(h, src, dst, msg, deg);
    }

    // 3. fused mean + 2-layer MLP + relu
    {
        int blocks = (N_NODES + M_TILE - 1) / M_TILE;
        sage_mlp<<<blocks, 256, 0, stream>>>(h, msg, deg, W1, b1, W2, b2, out);
    }
}

// Round 3
// 386.776 us; speedup vs baseline: 3.3831x; 3.3831x over previous
//
#include <hip/hip_runtime.h>

#define N_NODES 50000
#define E_EDGES 600000
#define IN_DIM  128
#define HID     256
#define OUT_DIM 128
#define M_TILE  32
#define SM_PAD  36   // LDS row stride (floats): %4==0 keeps float4 16B-aligned
#define CAP     64   // bucket capacity per node (deg ~ Poisson(12); P(>64) ~ 0, verified by bench)

// ---------------------------------------------------------------------------
// Kernel 1: zero the per-node edge counters (ws is poisoned 0xAA pre-launch).
// ---------------------------------------------------------------------------
__global__ void sage_zero_counts(int* __restrict__ counts) {
    int i = blockIdx.x * blockDim.x + threadIdx.x;
    int stride = gridDim.x * blockDim.x;
    for (int j = i; j < N_NODES; j += stride) counts[j] = 0;
}

// ---------------------------------------------------------------------------
// Kernel 2: bucket edges by dst. One thread per edge; 600k int atomics
// (vs 76.8M fp32 atomics in the scatter formulation).
// ---------------------------------------------------------------------------
__global__ void sage_fill(const int* __restrict__ src,
                          const int* __restrict__ dst,
                          int* __restrict__ counts,
                          int* __restrict__ bucket) {
    int e = blockIdx.x * blockDim.x + threadIdx.x;
    if (e >= E_EDGES) return;
    int d = dst[e];
    int slot = atomicAdd(counts + d, 1);
    if (slot < CAP) bucket[(size_t)d * CAP + slot] = src[e];
}

// ---------------------------------------------------------------------------
// Kernel 3: fused gather-mean + 2-layer MLP + relu.
// One block = 256 threads = 32 nodes.
//   Stage A: self features -> sm[0:128][m]; neighbor mean (gathered via
//            bucket, one wave per node, float2/lane) -> sm[128:256][m].
//   Stage B: register-tiled fp32 GEMM (identical to round 2).
// ---------------------------------------------------------------------------
__global__ void __launch_bounds__(256)
sage_mlp(const float* __restrict__ h,
         const int* __restrict__ counts,
         const int* __restrict__ bucket,
         const float* __restrict__ W1,
         const float* __restrict__ b1,
         const float* __restrict__ W2,
         const float* __restrict__ b2,
         float* __restrict__ out) {
    __shared__ float sm[2 * IN_DIM][SM_PAD];   // 36 KB

    const int t = threadIdx.x;
    const int base = blockIdx.x * M_TILE;
    const int i = t >> 5;     // 0..7
    const int j = t & 31;     // 0..31
    const int wave = t >> 6;  // 0..3
    const int lane = t & 63;  // 0..63

    // ---- Stage A1: self features. 2 nodes per iteration, fully coalesced.
    #pragma unroll 4
    for (int p = 0; p < 16; ++p) {
        int m = p * 2 + (t >> 7);
        int f = t & 127;
        int n = base + m;
        float v = (n < N_NODES) ? h[(size_t)n * IN_DIM + f] : 0.0f;
        sm[f][m] = v;
    }

    // ---- Stage A2: neighbor gather + mean. One wave per node, 8 nodes/wave.
    for (int m = wave; m < M_TILE; m += 4) {
        int n = base + m;
        float a0 = 0.0f, a1 = 0.0f;
        int dg = 0;
        if (n < N_NODES) {
            dg = counts[n];
            int entries = min(dg, CAP);
            const int* bk = bucket + (size_t)n * CAP;
            for (int e = 0; e < entries; ++e) {
                int s = bk[e];   // wave-uniform -> broadcast load
                const float2 hv = *(const float2*)(h + (size_t)s * IN_DIM + lane * 2);
                a0 += hv.x;
                a1 += hv.y;
            }
        }
        float inv = 1.0f / (float)max(dg, 1);
        sm[IN_DIM + lane * 2][m]     = a0 * inv;
        sm[IN_DIM + lane * 2 + 1][m] = a1 * inv;
    }
    __syncthreads();

    // ---- Stage B1: hid[m][c] = b1[c] + sum_k ht[m][k] * W1[k][c]
    float acc1[4][8];
    {
        const float4 bv0 = *(const float4*)(b1 + j * 8);
        const float4 bv1 = *(const float4*)(b1 + j * 8 + 4);
        #pragma unroll
        for (int mm = 0; mm < 4; ++mm) {
            acc1[mm][0] = bv0.x; acc1[mm][1] = bv0.y; acc1[mm][2] = bv0.z; acc1[mm][3] = bv0.w;
            acc1[mm][4] = bv1.x; acc1[mm][5] = bv1.y; acc1[mm][6] = bv1.z; acc1[mm][7] = bv1.w;
        }
    }
    for (int k = 0; k < 2 * IN_DIM; ++k) {
        const float4 a  = *(const float4*)&sm[k][i * 4];
        const float4 w0 = *(const float4*)(W1 + (size_t)k * HID + j * 8);
        const float4 w1 = *(const float4*)(W1 + (size_t)k * HID + j * 8 + 4);
        const float av[4] = {a.x, a.y, a.z, a.w};
        const float wv[8] = {w0.x, w0.y, w0.z, w0.w, w1.x, w1.y, w1.z, w1.w};
        #pragma unroll
        for (int mm = 0; mm < 4; ++mm)
            #pragma unroll
            for (int cc = 0; cc < 8; ++cc)
                acc1[mm][cc] = fmaf(av[mm], wv[cc], acc1[mm][cc]);
    }
    __syncthreads();

    // ---- store hid transposed back into sm: sm[c][m]
    #pragma unroll
    for (int cc = 0; cc < 8; ++cc)
        #pragma unroll
        for (int mm = 0; mm < 4; ++mm)
            sm[j * 8 + cc][i * 4 + mm] = acc1[mm][cc];
    __syncthreads();

    // ---- Stage B2: out[m][c] = relu(b2[c] + sum_k hid[m][k] * W2[k][c])
    float acc2[4][4];
    {
        const float4 bv = *(const float4*)(b2 + j * 4);
        #pragma unroll
        for (int mm = 0; mm < 4; ++mm) {
            acc2[mm][0] = bv.x; acc2[mm][1] = bv.y; acc2[mm][2] = bv.z; acc2[mm][3] = bv.w;
        }
    }
    for (int k = 0; k < HID; ++k) {
        const float4 a = *(const float4*)&sm[k][i * 4];
        const float4 w = *(const float4*)(W2 + (size_t)k * OUT_DIM + j * 4);
        const float av[4] = {a.x, a.y, a.z, a.w};
        const float wv[4] = {w.x, w.y, w.z, w.w};
        #pragma unroll
        for (int mm = 0; mm < 4; ++mm)
            #pragma unroll
            for (int cc = 0; cc < 4; ++cc)
                acc2[mm][cc] = fmaf(av[mm], wv[cc], acc2[mm][cc]);
    }

    #pragma unroll
    for (int mm = 0; mm < 4; ++mm) {
        int n = base + i * 4 + mm;
        if (n < N_NODES) {
            float4 o;
            o.x = fmaxf(acc2[mm][0], 0.0f);
            o.y = fmaxf(acc2[mm][1], 0.0f);
            o.z = fmaxf(acc2[mm][2], 0.0f);
            o.w = fmaxf(acc2[mm][3], 0.0f);
            *(float4*)(out + (size_t)n * OUT_DIM + j * 4) = o;
        }
    }
}

extern "C" void kernel_launch(void* const* d_in, const int* in_sizes, int n_in,
                              void* d_out, int out_size, void* d_ws, size_t ws_size,
                              hipStream_t stream) {
    const float* h   = (const float*)d_in[0];
    const int*   src = (const int*)d_in[1];
    const int*   dst = (const int*)d_in[2];
    const float* W1  = (const float*)d_in[3];
    const float* b1  = (const float*)d_in[4];
    const float* W2  = (const float*)d_in[5];
    const float* b2  = (const float*)d_in[6];
    float* out = (float*)d_out;

    // ws layout: counts [N ints] | bucket [N*CAP ints]  (~13 MB total)
    int* counts = (int*)d_ws;
    int* bucket = counts + N_NODES;

    sage_zero_counts<<<64, 256, 0, stream>>>(counts);

    sage_fill<<<(E_EDGES + 255) / 256, 256, 0, stream>>>(src, dst, counts, bucket);

    sage_mlp<<<(N_NODES + M_TILE - 1) / M_TILE, 256, 0, stream>>>(
        h, counts, bucket, W1, b1, W2, b2, out);
}

// Round 4
// 344.451 us; speedup vs baseline: 3.7988x; 1.1229x over previous
//
#include <hip/hip_runtime.h>

#define N_NODES 50000
#define E_EDGES 600000
#define IN_DIM  128
#define HID     256
#define OUT_DIM 128
#define M_TILE  32
#define SM_PAD  36   // LDS row stride (floats): %4==0 keeps float4 16B-aligned
#define CAP     64   // bucket capacity per node (deg ~ Poisson(12); max deg ~ 33)

// ---------------------------------------------------------------------------
// Kernel 1: zero the per-node edge counters (ws is poisoned 0xAA pre-launch).
// ---------------------------------------------------------------------------
__global__ void sage_zero_counts(int* __restrict__ counts) {
    int i = blockIdx.x * blockDim.x + threadIdx.x;
    if (i < N_NODES) counts[i] = 0;
}

// ---------------------------------------------------------------------------
// Kernel 2: bucket edges by dst (600k int atomics).
// ---------------------------------------------------------------------------
__global__ void sage_fill(const int* __restrict__ src,
                          const int* __restrict__ dst,
                          int* __restrict__ counts,
                          int* __restrict__ bucket) {
    int e = blockIdx.x * blockDim.x + threadIdx.x;
    if (e >= E_EDGES) return;
    int d = dst[e];
    int slot = atomicAdd(counts + d, 1);
    if (slot < CAP) bucket[(size_t)d * CAP + slot] = src[e];
}

// ---------------------------------------------------------------------------
// Kernel 3: neighbor gather + mean, throughput-shaped.
// 2 nodes per 256-thread block; 128 lanes per node (one float each, 512 B
// coalesced row reads). Indices prefetched 4-at-a-time (int4) so 4 row loads
// are in flight per chain step. Means are written into d_out (msg scratch):
// safe because the MLP block that reads row n's mean is the only writer of
// row n's output, and it reads before it writes.
// ---------------------------------------------------------------------------
__global__ void __launch_bounds__(256)
sage_gather(const float* __restrict__ h,
            const int* __restrict__ counts,
            const int* __restrict__ bucket,
            float* __restrict__ msg) {
    int node = blockIdx.x * 2 + (threadIdx.x >> 7);
    int f = threadIdx.x & 127;
    if (node >= N_NODES) return;

    int dg = counts[node];
    int entries = min(dg, CAP);
    const int* bk = bucket + (size_t)node * CAP;

    float acc = 0.0f;
    int e = 0;
    for (; e + 4 <= entries; e += 4) {
        const int4 s4 = *(const int4*)(bk + e);   // wave-uniform prefetch
        float v0 = h[(size_t)s4.x * IN_DIM + f];
        float v1 = h[(size_t)s4.y * IN_DIM + f];
        float v2 = h[(size_t)s4.z * IN_DIM + f];
        float v3 = h[(size_t)s4.w * IN_DIM + f];
        acc += v0; acc += v1; acc += v2; acc += v3;
    }
    for (; e < entries; ++e)
        acc += h[(size_t)bk[e] * IN_DIM + f];

    msg[(size_t)node * IN_DIM + f] = acc / (float)max(dg, 1);
}

// ---------------------------------------------------------------------------
// Kernel 4: fused mean-load + 2-layer MLP + relu (register-tiled fp32 GEMM).
// One block = 256 threads = 32 nodes. Stage A loads both halves coalesced.
// ---------------------------------------------------------------------------
__global__ void __launch_bounds__(256)
sage_mlp(const float* __restrict__ h,
         const float* __restrict__ msg,
         const float* __restrict__ W1,
         const float* __restrict__ b1,
         const float* __restrict__ W2,
         const float* __restrict__ b2,
         float* __restrict__ out) {
    __shared__ float sm[2 * IN_DIM][SM_PAD];   // 36 KB

    const int t = threadIdx.x;
    const int base = blockIdx.x * M_TILE;
    const int i = t >> 5;     // 0..7
    const int j = t & 31;     // 0..31

    // ---- Stage A: sm[k][m] = h_total[base+m][k], both halves coalesced ----
    {
        const int half = t >> 7;          // 0: self features, 1: neighbor mean
        const int f = t & 127;
        const float* srcp = half ? msg : h;
        #pragma unroll 8
        for (int m = 0; m < M_TILE; ++m) {
            int n = base + m;
            float v = (n < N_NODES) ? srcp[(size_t)n * IN_DIM + f] : 0.0f;
            sm[half * IN_DIM + f][m] = v;
        }
    }
    __syncthreads();

    // ---- layer 1: hid[m][c] = b1[c] + sum_k ht[m][k] * W1[k][c] -----------
    float acc1[4][8];
    {
        const float4 bv0 = *(const float4*)(b1 + j * 8);
        const float4 bv1 = *(const float4*)(b1 + j * 8 + 4);
        #pragma unroll
        for (int mm = 0; mm < 4; ++mm) {
            acc1[mm][0] = bv0.x; acc1[mm][1] = bv0.y; acc1[mm][2] = bv0.z; acc1[mm][3] = bv0.w;
            acc1[mm][4] = bv1.x; acc1[mm][5] = bv1.y; acc1[mm][6] = bv1.z; acc1[mm][7] = bv1.w;
        }
    }
    #pragma unroll 4
    for (int k = 0; k < 2 * IN_DIM; ++k) {
        const float4 a  = *(const float4*)&sm[k][i * 4];
        const float4 w0 = *(const float4*)(W1 + (size_t)k * HID + j * 8);
        const float4 w1 = *(const float4*)(W1 + (size_t)k * HID + j * 8 + 4);
        const float av[4] = {a.x, a.y, a.z, a.w};
        const float wv[8] = {w0.x, w0.y, w0.z, w0.w, w1.x, w1.y, w1.z, w1.w};
        #pragma unroll
        for (int mm = 0; mm < 4; ++mm)
            #pragma unroll
            for (int cc = 0; cc < 8; ++cc)
                acc1[mm][cc] = fmaf(av[mm], wv[cc], acc1[mm][cc]);
    }
    __syncthreads();

    // ---- store hid transposed back into sm: sm[c][m] ----------------------
    #pragma unroll
    for (int cc = 0; cc < 8; ++cc)
        #pragma unroll
        for (int mm = 0; mm < 4; ++mm)
            sm[j * 8 + cc][i * 4 + mm] = acc1[mm][cc];
    __syncthreads();

    // ---- layer 2: out[m][c] = relu(b2[c] + sum_k hid[m][k] * W2[k][c]) ----
    float acc2[4][4];
    {
        const float4 bv = *(const float4*)(b2 + j * 4);
        #pragma unroll
        for (int mm = 0; mm < 4; ++mm) {
            acc2[mm][0] = bv.x; acc2[mm][1] = bv.y; acc2[mm][2] = bv.z; acc2[mm][3] = bv.w;
        }
    }
    #pragma unroll 4
    for (int k = 0; k < HID; ++k) {
        const float4 a = *(const float4*)&sm[k][i * 4];
        const float4 w = *(const float4*)(W2 + (size_t)k * OUT_DIM + j * 4);
        const float av[4] = {a.x, a.y, a.z, a.w};
        const float wv[4] = {w.x, w.y, w.z, w.w};
        #pragma unroll
        for (int mm = 0; mm < 4; ++mm)
            #pragma unroll
            for (int cc = 0; cc < 4; ++cc)
                acc2[mm][cc] = fmaf(av[mm], wv[cc], acc2[mm][cc]);
    }

    #pragma unroll
    for (int mm = 0; mm < 4; ++mm) {
        int n = base + i * 4 + mm;
        if (n < N_NODES) {
            float4 o;
            o.x = fmaxf(acc2[mm][0], 0.0f);
            o.y = fmaxf(acc2[mm][1], 0.0f);
            o.z = fmaxf(acc2[mm][2], 0.0f);
            o.w = fmaxf(acc2[mm][3], 0.0f);
            *(float4*)(out + (size_t)n * OUT_DIM + j * 4) = o;
        }
    }
}

extern "C" void kernel_launch(void* const* d_in, const int* in_sizes, int n_in,
                              void* d_out, int out_size, void* d_ws, size_t ws_size,
                              hipStream_t stream) {
    const float* h   = (const float*)d_in[0];
    const int*   src = (const int*)d_in[1];
    const int*   dst = (const int*)d_in[2];
    const float* W1  = (const float*)d_in[3];
    const float* b1  = (const float*)d_in[4];
    const float* W2  = (const float*)d_in[5];
    const float* b2  = (const float*)d_in[6];
    float* out = (float*)d_out;

    // ws layout: counts [N ints] | bucket [N*CAP ints]  (~13 MB)
    int* counts = (int*)d_ws;
    int* bucket = counts + N_NODES;

    // msg scratch lives in d_out (overwritten row-by-row by sage_mlp after read)
    float* msg = out;

    sage_zero_counts<<<(N_NODES + 255) / 256, 256, 0, stream>>>(counts);

    sage_fill<<<(E_EDGES + 255) / 256, 256, 0, stream>>>(src, dst, counts, bucket);

    sage_gather<<<(N_NODES + 1) / 2, 256, 0, stream>>>(h, counts, bucket, msg);

    sage_mlp<<<(N_NODES + M_TILE - 1) / M_TILE, 256, 0, stream>>>(
        h, msg, W1, b1, W2, b2, out);
}

// Round 5
// 266.536 us; speedup vs baseline: 4.9093x; 1.2923x over previous
//
#include <hip/hip_runtime.h>

#define N_NODES 50000
#define E_EDGES 600000
#define IN_DIM  128
#define HID     256
#define OUT_DIM 128
#define CAP     64    // bucket capacity (deg ~ Poisson(12), max ~35)
#define MT      64    // rows per MLP block

typedef __bf16 bf16x8 __attribute__((ext_vector_type(8)));
typedef float  f32x4  __attribute__((ext_vector_type(4)));

__device__ __forceinline__ unsigned short f2bf(float f) {
    union { float f; unsigned int i; } v; v.f = f;
    unsigned int b = v.i;
    b += 0x7fffu + ((b >> 16) & 1u);   // RNE
    return (unsigned short)(b >> 16);
}
__device__ __forceinline__ float bf2f(unsigned short u) {
    union { unsigned int i; float f; } v; v.i = ((unsigned int)u) << 16; return v.f;
}

// ---------------------------------------------------------------------------
// Kernel: bucket edges by dst (600k int atomics). counts zeroed by memsetAsync.
// ---------------------------------------------------------------------------
__global__ void sage_fill(const int* __restrict__ src,
                          const int* __restrict__ dst,
                          int* __restrict__ counts,
                          int* __restrict__ bucket) {
    int e = blockIdx.x * blockDim.x + threadIdx.x;
    if (e >= E_EDGES) return;
    int d = dst[e];
    int slot = atomicAdd(counts + d, 1);
    if (slot < CAP) bucket[(size_t)d * CAP + slot] = src[e];
}

// ---------------------------------------------------------------------------
// Kernel: h (fp32) -> ht[n][0:128] (bf16). ht lives in d_out (row = 512 B).
// ---------------------------------------------------------------------------
__global__ void sage_hcvt(const float* __restrict__ h, unsigned short* __restrict__ ht) {
    int idx = blockIdx.x * 256 + threadIdx.x;       // 50000*32 groups of 4
    if (idx >= N_NODES * 32) return;
    int n = idx >> 5, g = idx & 31;
    const float4 v = *(const float4*)(h + (size_t)n * IN_DIM + g * 4);
    ushort4 o;
    o.x = f2bf(v.x); o.y = f2bf(v.y); o.z = f2bf(v.z); o.w = f2bf(v.w);
    *(ushort4*)(ht + (size_t)n * 256 + g * 4) = o;
}

// ---------------------------------------------------------------------------
// Kernel: W1 [256][256], W2 [256][128] (fp32) -> transposed bf16:
//   w1t[n][k] = W1[k][n], w2t[o][k] = W2[k][o]  (B-fragments become 16 B loads)
// ---------------------------------------------------------------------------
__global__ void sage_wcvt(const float* __restrict__ W1, const float* __restrict__ W2,
                          unsigned short* __restrict__ w1t, unsigned short* __restrict__ w2t) {
    int i = blockIdx.x * 256 + threadIdx.x;
    if (i < HID * HID) {
        int n = i >> 8, k = i & 255;
        w1t[i] = f2bf(W1[(size_t)k * HID + n]);
    } else {
        int j = i - HID * HID;
        if (j < OUT_DIM * HID) {
            int o = j >> 8, k = j & 255;
            w2t[j] = f2bf(W2[(size_t)k * OUT_DIM + o]);
        }
    }
}

// ---------------------------------------------------------------------------
// Kernel: neighbor gather + mean in bf16. 32 lanes per node (ushort4/lane),
// 8 nodes per 256-thread block, indices prefetched int4 (4 row-loads in
// flight). Reads ht[s][0:128] (bf16, 256 B/row), writes ht[n][128:256].
// ---------------------------------------------------------------------------
__global__ void __launch_bounds__(256)
sage_gather(const int* __restrict__ counts,
            const int* __restrict__ bucket,
            unsigned short* ht) {
    int node = blockIdx.x * 8 + (threadIdx.x >> 5);
    int l = threadIdx.x & 31;
    if (node >= N_NODES) return;

    int dg = counts[node];
    int entries = min(dg, CAP);
    const int* bk = bucket + (size_t)node * CAP;

    float a0 = 0.f, a1 = 0.f, a2 = 0.f, a3 = 0.f;
    int e = 0;
    for (; e + 4 <= entries; e += 4) {
        const int4 s = *(const int4*)(bk + e);
        const ushort4 v0 = *(const ushort4*)(ht + (size_t)s.x * 256 + l * 4);
        const ushort4 v1 = *(const ushort4*)(ht + (size_t)s.y * 256 + l * 4);
        const ushort4 v2 = *(const ushort4*)(ht + (size_t)s.z * 256 + l * 4);
        const ushort4 v3 = *(const ushort4*)(ht + (size_t)s.w * 256 + l * 4);
        a0 += bf2f(v0.x) + bf2f(v1.x) + bf2f(v2.x) + bf2f(v3.x);
        a1 += bf2f(v0.y) + bf2f(v1.y) + bf2f(v2.y) + bf2f(v3.y);
        a2 += bf2f(v0.z) + bf2f(v1.z) + bf2f(v2.z) + bf2f(v3.z);
        a3 += bf2f(v0.w) + bf2f(v1.w) + bf2f(v2.w) + bf2f(v3.w);
    }
    for (; e < entries; ++e) {
        const ushort4 v = *(const ushort4*)(ht + (size_t)bk[e] * 256 + l * 4);
        a0 += bf2f(v.x); a1 += bf2f(v.y); a2 += bf2f(v.z); a3 += bf2f(v.w);
    }
    float inv = 1.0f / (float)max(dg, 1);
    ushort4 o;
    o.x = f2bf(a0 * inv); o.y = f2bf(a1 * inv);
    o.z = f2bf(a2 * inv); o.w = f2bf(a3 * inv);
    *(ushort4*)(ht + (size_t)node * 256 + 128 + l * 4) = o;
}

// ---------------------------------------------------------------------------
// Kernel: fused 2-layer MLP via v_mfma_f32_16x16x32_bf16.
// Block = 256 threads = 4 waves; wave owns 16 rows (one M16 strip).
// Layer1: 16 N-tiles x 8 K-steps; A-frags in regs, B streamed from w1t (L2).
// hid -> LDS (bf16, 528 B row stride) -> layer2 A-frags.
// out (fp32) overwrites ht rows: safe, A-frags are read before any store.
// Layouts (guide, m89/m120): A[m=lane&15][k=(lane>>4)*8+j],
//   B[k=(lane>>4)*8+j][n=lane&15], C/D col=lane&15 row=(lane>>4)*4+reg.
// ---------------------------------------------------------------------------
__global__ void __launch_bounds__(256)
sage_mlp(const unsigned short* ht,           // aliases out!
         const unsigned short* __restrict__ w1t,
         const float* __restrict__ b1,
         const unsigned short* __restrict__ w2t,
         const float* __restrict__ b2,
         float* out) {
    __shared__ unsigned short hid_s[4][16][264];   // 528 B row stride, 33 KB

    const int t = threadIdx.x;
    const int wave = t >> 6;
    const int lane = t & 63;
    const int r = lane & 15;
    const int q = lane >> 4;
    const int row = blockIdx.x * MT + wave * 16 + r;
    const int row_c = min(row, N_NODES - 1);

    // ---- A-frags for all 8 K-steps (16 B contiguous loads) -----------------
    bf16x8 a[8];
    {
        const bf16x8* ap = (const bf16x8*)(ht + (size_t)row_c * 256);
        #pragma unroll
        for (int ki = 0; ki < 8; ++ki) a[ki] = ap[ki * 4 + q];   // k = ki*32 + q*8
    }

    // ---- Layer 1: hid^strip = A (16x256) @ W1 (256x256) --------------------
    f32x4 c1[16];
    #pragma unroll
    for (int i = 0; i < 16; ++i) c1[i] = (f32x4){0.f, 0.f, 0.f, 0.f};

    #pragma unroll
    for (int ki = 0; ki < 8; ++ki) {
        #pragma unroll
        for (int nt = 0; nt < 16; ++nt) {
            bf16x8 b = *(const bf16x8*)(w1t + (size_t)(nt * 16 + r) * 256 + ki * 32 + q * 8);
            c1[nt] = __builtin_amdgcn_mfma_f32_16x16x32_bf16(a[ki], b, c1[nt], 0, 0, 0);
        }
    }

    // ---- epilogue 1: + b1, -> bf16 -> LDS (C layout -> row-major) ----------
    #pragma unroll
    for (int nt = 0; nt < 16; ++nt) {
        float bias = b1[nt * 16 + r];
        #pragma unroll
        for (int rr = 0; rr < 4; ++rr)
            hid_s[wave][q * 4 + rr][nt * 16 + r] = f2bf(c1[nt][rr] + bias);
    }
    __syncthreads();

    // ---- Layer 2: out^strip = hid (16x256) @ W2 (256x128) ------------------
    f32x4 c2[8];
    #pragma unroll
    for (int i = 0; i < 8; ++i) c2[i] = (f32x4){0.f, 0.f, 0.f, 0.f};

    #pragma unroll
    for (int ki = 0; ki < 8; ++ki) {
        bf16x8 ah = *(const bf16x8*)&hid_s[wave][r][ki * 32 + q * 8];
        #pragma unroll
        for (int nt = 0; nt < 8; ++nt) {
            bf16x8 b = *(const bf16x8*)(w2t + (size_t)(nt * 16 + r) * 256 + ki * 32 + q * 8);
            c2[nt] = __builtin_amdgcn_mfma_f32_16x16x32_bf16(ah, b, c2[nt], 0, 0, 0);
        }
    }

    // ---- epilogue 2: + b2, relu, store fp32 --------------------------------
    #pragma unroll
    for (int nt = 0; nt < 8; ++nt) {
        int col = nt * 16 + r;
        float bias = b2[col];
        #pragma unroll
        for (int rr = 0; rr < 4; ++rr) {
            int n = blockIdx.x * MT + wave * 16 + q * 4 + rr;
            if (n < N_NODES)
                out[(size_t)n * OUT_DIM + col] = fmaxf(c2[nt][rr] + bias, 0.0f);
        }
    }
}

extern "C" void kernel_launch(void* const* d_in, const int* in_sizes, int n_in,
                              void* d_out, int out_size, void* d_ws, size_t ws_size,
                              hipStream_t stream) {
    const float* h   = (const float*)d_in[0];
    const int*   src = (const int*)d_in[1];
    const int*   dst = (const int*)d_in[2];
    const float* W1  = (const float*)d_in[3];
    const float* b1  = (const float*)d_in[4];
    const float* W2  = (const float*)d_in[5];
    const float* b2  = (const float*)d_in[6];
    float* out = (float*)d_out;

    // ht (bf16 [50000][256] = 25.6 MB) lives in d_out; overwritten by fp32 out.
    unsigned short* ht = (unsigned short*)d_out;

    // ws: counts [50000 int] | bucket [50000*64 int] | w1t [65536 bf16] | w2t [32768 bf16]
    int* counts = (int*)d_ws;
    int* bucket = counts + N_NODES;                    // byte 200000 (16-aligned)
    unsigned short* w1t = (unsigned short*)(bucket + (size_t)N_NODES * CAP);
    unsigned short* w2t = w1t + HID * HID;

    hipMemsetAsync(counts, 0, N_NODES * sizeof(int), stream);

    sage_fill<<<(E_EDGES + 255) / 256, 256, 0, stream>>>(src, dst, counts, bucket);

    sage_hcvt<<<(N_NODES * 32 + 255) / 256, 256, 0, stream>>>(h, ht);

    sage_wcvt<<<(HID * HID + OUT_DIM * HID + 255) / 256, 256, 0, stream>>>(W1, W2, w1t, w2t);

    sage_gather<<<(N_NODES + 7) / 8, 256, 0, stream>>>(counts, bucket, ht);

    sage_mlp<<<(N_NODES + MT - 1) / MT, 256, 0, stream>>>(ht, w1t, b1, w2t, b2, out);
}

// Round 6
// 185.066 us; speedup vs baseline: 7.0705x; 1.4402x over previous
//
#include <hip/hip_runtime.h>

#define N_NODES 50000
#define E_EDGES 600000
#define IN_DIM  128
#define HID     256
#define OUT_DIM 128
#define CAP     64    // bucket capacity (deg ~ Poisson(12), max ~35)

typedef __bf16 bf16x8 __attribute__((ext_vector_type(8)));
typedef float  f32x16 __attribute__((ext_vector_type(16)));

__device__ __forceinline__ unsigned short f2bf(float f) {
    union { float f; unsigned int i; } v; v.f = f;
    unsigned int b = v.i;
    b += 0x7fffu + ((b >> 16) & 1u);   // RNE
    return (unsigned short)(b >> 16);
}
__device__ __forceinline__ float bf2f(unsigned short u) {
    union { unsigned int i; float f; } v; v.i = ((unsigned int)u) << 16; return v.f;
}

// ---------------------------------------------------------------------------
// Bucket edges by dst (600k int atomics). counts zeroed by memsetAsync.
// ---------------------------------------------------------------------------
__global__ void sage_fill(const int* __restrict__ src,
                          const int* __restrict__ dst,
                          int* __restrict__ counts,
                          int* __restrict__ bucket) {
    int e = blockIdx.x * blockDim.x + threadIdx.x;
    if (e >= E_EDGES) return;
    int d = dst[e];
    int slot = atomicAdd(counts + d, 1);
    if (slot < CAP) bucket[(size_t)d * CAP + slot] = src[e];
}

// ---------------------------------------------------------------------------
// h (fp32) -> ht[n][0:128] (bf16). ht lives in d_out (row = 512 B).
// ---------------------------------------------------------------------------
__global__ void sage_hcvt(const float* __restrict__ h, unsigned short* __restrict__ ht) {
    int idx = blockIdx.x * 256 + threadIdx.x;
    if (idx >= N_NODES * 32) return;
    int n = idx >> 5, g = idx & 31;
    const float4 v = *(const float4*)(h + (size_t)n * IN_DIM + g * 4);
    ushort4 o;
    o.x = f2bf(v.x); o.y = f2bf(v.y); o.z = f2bf(v.z); o.w = f2bf(v.w);
    *(ushort4*)(ht + (size_t)n * 256 + g * 4) = o;
}

// ---------------------------------------------------------------------------
// W1 [256][256], W2 [256][128] (fp32) -> bf16 pre-swizzled into MFMA
// B-fragment staging order, so the MLP's global->LDS copy is an identity:
//   w1sw flat = (((c*4 + ks)*2 + g)*256 + n)*8 + j,  k = c*64 + ks*16 + g*8 + j
//   w2sw flat = (((c*8 + ks)*2 + g)*128 + n)*8 + j,  k = c*128 + ks*16 + g*8 + j
// ---------------------------------------------------------------------------
__global__ void sage_wcvt(const float* __restrict__ W1, const float* __restrict__ W2,
                          unsigned short* __restrict__ w1sw, unsigned short* __restrict__ w2sw) {
    int i = blockIdx.x * 256 + threadIdx.x;
    if (i < 65536) {
        int j = i & 7, n = (i >> 3) & 255, g = (i >> 11) & 1, ks = (i >> 12) & 3, c = i >> 14;
        int k = c * 64 + ks * 16 + g * 8 + j;
        w1sw[i] = f2bf(W1[(size_t)k * HID + n]);
    } else {
        int i2 = i - 65536;
        if (i2 < 32768) {
            int j = i2 & 7, n = (i2 >> 3) & 127, g = (i2 >> 10) & 1, ks = (i2 >> 11) & 7, c = (i2 >> 14) & 1;
            int k = c * 128 + ks * 16 + g * 8 + j;
            w2sw[i2] = f2bf(W2[(size_t)k * OUT_DIM + n]);
        }
    }
}

// ---------------------------------------------------------------------------
// Neighbor gather + mean in bf16. 32 lanes/node (ushort4/lane), 8 nodes per
// block, int4 index prefetch (4 row loads in flight). Writes ht[n][128:256].
// ---------------------------------------------------------------------------
__global__ void __launch_bounds__(256)
sage_gather(const int* __restrict__ counts,
            const int* __restrict__ bucket,
            unsigned short* ht) {
    int node = blockIdx.x * 8 + (threadIdx.x >> 5);
    int l = threadIdx.x & 31;
    if (node >= N_NODES) return;

    int dg = counts[node];
    int entries = min(dg, CAP);
    const int* bk = bucket + (size_t)node * CAP;

    float a0 = 0.f, a1 = 0.f, a2 = 0.f, a3 = 0.f;
    int e = 0;
    for (; e + 4 <= entries; e += 4) {
        const int4 s = *(const int4*)(bk + e);
        const ushort4 v0 = *(const ushort4*)(ht + (size_t)s.x * 256 + l * 4);
        const ushort4 v1 = *(const ushort4*)(ht + (size_t)s.y * 256 + l * 4);
        const ushort4 v2 = *(const ushort4*)(ht + (size_t)s.z * 256 + l * 4);
        const ushort4 v3 = *(const ushort4*)(ht + (size_t)s.w * 256 + l * 4);
        a0 += bf2f(v0.x) + bf2f(v1.x) + bf2f(v2.x) + bf2f(v3.x);
        a1 += bf2f(v0.y) + bf2f(v1.y) + bf2f(v2.y) + bf2f(v3.y);
        a2 += bf2f(v0.z) + bf2f(v1.z) + bf2f(v2.z) + bf2f(v3.z);
        a3 += bf2f(v0.w) + bf2f(v1.w) + bf2f(v2.w) + bf2f(v3.w);
    }
    for (; e < entries; ++e) {
        const ushort4 v = *(const ushort4*)(ht + (size_t)bk[e] * 256 + l * 4);
        a0 += bf2f(v.x); a1 += bf2f(v.y); a2 += bf2f(v.z); a3 += bf2f(v.w);
    }
    float inv = 1.0f / (float)max(dg, 1);
    ushort4 o;
    o.x = f2bf(a0 * inv); o.y = f2bf(a1 * inv);
    o.z = f2bf(a2 * inv); o.w = f2bf(a3 * inv);
    *(ushort4*)(ht + (size_t)node * 256 + 128 + l * 4) = o;
}

// ---------------------------------------------------------------------------
// Fused 2-layer MLP via v_mfma_f32_32x32x16_bf16, LDS-staged weights.
// Block = 256 threads = 4 waves = 32 rows; wave `nw` owns a 64-col slice of
// layer 1 (2 n-tiles) and a 32-col slice of layer 2 (1 n-tile).
// W1 staged in 4 x 32KB chunks, W2 in 2 x 32KB chunks (shared 32KB buffer,
// identity copy from the pre-swizzled global layout). hid (32x256 bf16) in
// LDS, 264-short row stride: conflict-free writes, 4-way (1.58x) reads.
// Layouts (verified pattern): A[m=lane&31][k=(lane>>5)*8+j],
//   B[k=(lane>>5)*8+j][n=lane&31], C/D col=lane&31, row=(reg&3)+8*(reg>>2)+4*(lane>>5).
// out (fp32) overwrites ht rows: safe, A-frags preloaded before any store,
// and blocks only touch their own 32 rows.
// ---------------------------------------------------------------------------
__global__ void __launch_bounds__(256)
sage_mlp(const unsigned short* ht,            // aliases out!
         const unsigned short* __restrict__ w1sw,
         const unsigned short* __restrict__ w2sw,
         const float* __restrict__ b1,
         const float* __restrict__ b2,
         float* out) {
    __shared__ unsigned short wbuf[16384];      // 32 KB weight staging
    __shared__ unsigned short hid_s[32][264];   // 16.5 KB hidden tile

    const int t = threadIdx.x;
    const int nw = t >> 6;        // wave id = N-slice
    const int lane = t & 63;
    const int lr = lane & 31;
    const int lg = lane >> 5;
    const int base = blockIdx.x * 32;
    const int row_c = min(base + lr, N_NODES - 1);

    // ---- A-fragments for all 16 K-steps (16B contiguous loads) -------------
    bf16x8 a[16];
    {
        const unsigned short* ap = ht + (size_t)row_c * 256 + lg * 8;
        #pragma unroll
        for (int ks = 0; ks < 16; ++ks)
            a[ks] = *(const bf16x8*)(ap + ks * 16);
    }

    // ---- Layer 1: hid = A (32x256) @ W1 (256x256), wave owns 64 cols -------
    f32x16 c1[2];
    #pragma unroll
    for (int e = 0; e < 16; ++e) { c1[0][e] = 0.f; c1[1][e] = 0.f; }

    #pragma unroll
    for (int c = 0; c < 4; ++c) {
        if (c) __syncthreads();               // prior chunk's reads done
        {
            const bf16x8* gsrc = (const bf16x8*)(w1sw + c * 16384);
            #pragma unroll
            for (int i = 0; i < 8; ++i) {
                int off16 = i * 256 + t;
                *(bf16x8*)(wbuf + off16 * 8) = gsrc[off16];
            }
        }
        __syncthreads();                      // staged chunk visible
        #pragma unroll
        for (int ks = 0; ks < 4; ++ks) {
            #pragma unroll
            for (int nt = 0; nt < 2; ++nt) {
                int n = nw * 64 + nt * 32 + lr;
                bf16x8 b = *(const bf16x8*)(wbuf + (((ks * 2 + lg) * 256) + n) * 8);
                c1[nt] = __builtin_amdgcn_mfma_f32_32x32x16_bf16(a[c * 4 + ks], b, c1[nt], 0, 0, 0);
            }
        }
    }

    // ---- epilogue 1: + b1 -> bf16 -> hid_s (row-major [m][k]) --------------
    #pragma unroll
    for (int nt = 0; nt < 2; ++nt) {
        int col = nw * 64 + nt * 32 + lr;
        float bias = b1[col];
        #pragma unroll
        for (int reg = 0; reg < 16; ++reg) {
            int m = (reg & 3) + 8 * (reg >> 2) + 4 * lg;
            hid_s[m][col] = f2bf(c1[nt][reg] + bias);
        }
    }
    __syncthreads();    // hid visible + last W1 chunk reads done (wbuf free)

    // ---- Layer 2: out = hid (32x256) @ W2 (256x128), wave owns 32 cols -----
    f32x16 c2;
    #pragma unroll
    for (int e = 0; e < 16; ++e) c2[e] = 0.f;

    #pragma unroll
    for (int c = 0; c < 2; ++c) {
        if (c) __syncthreads();
        {
            const bf16x8* gsrc = (const bf16x8*)(w2sw + c * 16384);
            #pragma unroll
            for (int i = 0; i < 8; ++i) {
                int off16 = i * 256 + t;
                *(bf16x8*)(wbuf + off16 * 8) = gsrc[off16];
            }
        }
        __syncthreads();
        #pragma unroll
        for (int ks = 0; ks < 8; ++ks) {
            bf16x8 ah = *(const bf16x8*)(&hid_s[lr][c * 128 + ks * 16 + lg * 8]);
            bf16x8 b  = *(const bf16x8*)(wbuf + ((ks * 2 + lg) * 128 + nw * 32 + lr) * 8);
            c2 = __builtin_amdgcn_mfma_f32_32x32x16_bf16(ah, b, c2, 0, 0, 0);
        }
    }

    // ---- epilogue 2: + b2, relu, store fp32 --------------------------------
    {
        int col = nw * 32 + lr;
        float bias = b2[col];
        #pragma unroll
        for (int reg = 0; reg < 16; ++reg) {
            int m = (reg & 3) + 8 * (reg >> 2) + 4 * lg;
            int n = base + m;
            if (n < N_NODES)
                out[(size_t)n * OUT_DIM + col] = fmaxf(c2[reg] + bias, 0.0f);
        }
    }
}

extern "C" void kernel_launch(void* const* d_in, const int* in_sizes, int n_in,
                              void* d_out, int out_size, void* d_ws, size_t ws_size,
                              hipStream_t stream) {
    const float* h   = (const float*)d_in[0];
    const int*   src = (const int*)d_in[1];
    const int*   dst = (const int*)d_in[2];
    const float* W1  = (const float*)d_in[3];
    const float* b1  = (const float*)d_in[4];
    const float* W2  = (const float*)d_in[5];
    const float* b2  = (const float*)d_in[6];
    float* out = (float*)d_out;

    // ht (bf16 [50000][256] = 25.6 MB) lives in d_out; overwritten by fp32 out.
    unsigned short* ht = (unsigned short*)d_out;

    // ws: counts [50000 int] | bucket [50000*64 int] | w1sw [65536 bf16] | w2sw [32768 bf16]
    int* counts = (int*)d_ws;
    int* bucket = counts + N_NODES;
    unsigned short* w1sw = (unsigned short*)(bucket + (size_t)N_NODES * CAP);  // 16B-aligned
    unsigned short* w2sw = w1sw + 65536;

    hipMemsetAsync(counts, 0, N_NODES * sizeof(int), stream);

    sage_fill<<<(E_EDGES + 255) / 256, 256, 0, stream>>>(src, dst, counts, bucket);

    sage_hcvt<<<(N_NODES * 32 + 255) / 256, 256, 0, stream>>>(h, ht);

    sage_wcvt<<<(65536 + 32768 + 255) / 256, 256, 0, stream>>>(W1, W2, w1sw, w2sw);

    sage_gather<<<(N_NODES + 7) / 8, 256, 0, stream>>>(counts, bucket, ht);

    sage_mlp<<<(N_NODES + 31) / 32, 256, 0, stream>>>(ht, w1sw, w2sw, b1, b2, out);
}

// Round 7
// 180.949 us; speedup vs baseline: 7.2314x; 1.0228x over previous
//
#include <hip/hip_runtime.h>

#define N_NODES 50000
#define E_EDGES 600000
#define IN_DIM  128
#define HID     256
#define OUT_DIM 128
#define CAP     64    // bucket capacity (deg ~ Poisson(12), max ~35)

#define NB_FILL 2344  // (E_EDGES+255)/256
#define NB_HCVT 6250  // (N_NODES*32+255)/256
#define NB_WCVT 384   // (65536+32768)/256

typedef __bf16 bf16x8 __attribute__((ext_vector_type(8)));
typedef float  f32x16 __attribute__((ext_vector_type(16)));

__device__ __forceinline__ unsigned short f2bf(float f) {
    union { float f; unsigned int i; } v; v.f = f;
    unsigned int b = v.i;
    b += 0x7fffu + ((b >> 16) & 1u);   // RNE
    return (unsigned short)(b >> 16);
}
__device__ __forceinline__ float bf2f(unsigned short u) {
    union { unsigned int i; float f; } v; v.i = ((unsigned int)u) << 16; return v.f;
}

// ---------------------------------------------------------------------------
// Fused prep: [fill buckets] + [h fp32->bf16] + [W1/W2 -> swizzled bf16].
// The three jobs are independent; one launch lets their traffic overlap.
//   w1sw flat = (((c*4 + ks)*2 + g)*256 + n)*8 + j,  k = c*64 + ks*16 + g*8 + j
//   w2sw flat = (((c*8 + ks)*2 + g)*128 + n)*8 + j,  k = c*128 + ks*16 + g*8 + j
// ---------------------------------------------------------------------------
__global__ void __launch_bounds__(256)
sage_prep(const int* __restrict__ src, const int* __restrict__ dst,
          int* __restrict__ counts, int* __restrict__ bucket,
          const float* __restrict__ h, unsigned short* __restrict__ ht,
          const float* __restrict__ W1, const float* __restrict__ W2,
          unsigned short* __restrict__ w1sw, unsigned short* __restrict__ w2sw) {
    int b = blockIdx.x;
    if (b < NB_FILL) {
        int e = b * 256 + threadIdx.x;
        if (e < E_EDGES) {
            int d = dst[e];
            int slot = atomicAdd(counts + d, 1);
            if (slot < CAP) bucket[(size_t)d * CAP + slot] = src[e];
        }
    } else if (b < NB_FILL + NB_HCVT) {
        int idx = (b - NB_FILL) * 256 + threadIdx.x;
        if (idx < N_NODES * 32) {
            int n = idx >> 5, g = idx & 31;
            const float4 v = *(const float4*)(h + (size_t)n * IN_DIM + g * 4);
            ushort4 o;
            o.x = f2bf(v.x); o.y = f2bf(v.y); o.z = f2bf(v.z); o.w = f2bf(v.w);
            *(ushort4*)(ht + (size_t)n * 256 + g * 4) = o;
        }
    } else {
        int i = (b - NB_FILL - NB_HCVT) * 256 + threadIdx.x;
        if (i < 65536) {
            int j = i & 7, n = (i >> 3) & 255, g = (i >> 11) & 1, ks = (i >> 12) & 3, c = i >> 14;
            int k = c * 64 + ks * 16 + g * 8 + j;
            w1sw[i] = f2bf(W1[(size_t)k * HID + n]);
        } else {
            int i2 = i - 65536;
            int j = i2 & 7, n = (i2 >> 3) & 127, g = (i2 >> 10) & 1, ks = (i2 >> 11) & 7, c = (i2 >> 14) & 1;
            int k = c * 128 + ks * 16 + g * 8 + j;
            w2sw[i2] = f2bf(W2[(size_t)k * OUT_DIM + n]);
        }
    }
}

// ---------------------------------------------------------------------------
// Neighbor gather + mean in bf16. 32 lanes/node (ushort4/lane), 8 nodes per
// block, int4 index prefetch (4 row loads in flight). Writes ht[n][128:256].
// ---------------------------------------------------------------------------
__global__ void __launch_bounds__(256)
sage_gather(const int* __restrict__ counts,
            const int* __restrict__ bucket,
            unsigned short* ht) {
    int node = blockIdx.x * 8 + (threadIdx.x >> 5);
    int l = threadIdx.x & 31;
    if (node >= N_NODES) return;

    int dg = counts[node];
    int entries = min(dg, CAP);
    const int* bk = bucket + (size_t)node * CAP;

    float a0 = 0.f, a1 = 0.f, a2 = 0.f, a3 = 0.f;
    int e = 0;
    for (; e + 4 <= entries; e += 4) {
        const int4 s = *(const int4*)(bk + e);
        const ushort4 v0 = *(const ushort4*)(ht + (size_t)s.x * 256 + l * 4);
        const ushort4 v1 = *(const ushort4*)(ht + (size_t)s.y * 256 + l * 4);
        const ushort4 v2 = *(const ushort4*)(ht + (size_t)s.z * 256 + l * 4);
        const ushort4 v3 = *(const ushort4*)(ht + (size_t)s.w * 256 + l * 4);
        a0 += bf2f(v0.x) + bf2f(v1.x) + bf2f(v2.x) + bf2f(v3.x);
        a1 += bf2f(v0.y) + bf2f(v1.y) + bf2f(v2.y) + bf2f(v3.y);
        a2 += bf2f(v0.z) + bf2f(v1.z) + bf2f(v2.z) + bf2f(v3.z);
        a3 += bf2f(v0.w) + bf2f(v1.w) + bf2f(v2.w) + bf2f(v3.w);
    }
    for (; e < entries; ++e) {
        const ushort4 v = *(const ushort4*)(ht + (size_t)bk[e] * 256 + l * 4);
        a0 += bf2f(v.x); a1 += bf2f(v.y); a2 += bf2f(v.z); a3 += bf2f(v.w);
    }
    float inv = 1.0f / (float)max(dg, 1);
    ushort4 o;
    o.x = f2bf(a0 * inv); o.y = f2bf(a1 * inv);
    o.z = f2bf(a2 * inv); o.w = f2bf(a3 * inv);
    *(ushort4*)(ht + (size_t)node * 256 + 128 + l * 4) = o;
}

// ---------------------------------------------------------------------------
// Fused 2-layer MLP via v_mfma_f32_32x32x16_bf16, LDS-staged weights.
// Block = 256 threads = 4 waves = 64 rows (2 strips of 32).
// Wave nw owns a 64-col slice of layer 1 and a 32-col slice of layer 2, and
// computes BOTH row strips -> each LDS B-fragment feeds 2 MFMAs (2:1 ratio).
// A-frags reloaded per K-chunk from global (ht rows, L1-hot) to cap VGPRs.
// W1 staged 4 x 32KB, W2 2 x 32KB (identity copy from pre-swizzled layout).
// hid (64x256 bf16) in LDS, 264-short stride.
// Layouts: A[m=lane&31][k=(lane>>5)*8+j], B[k][n=lane&31],
//   C/D col=lane&31, row=(reg&3)+8*(reg>>2)+4*(lane>>5).
// out (fp32) overwrites ht rows: safe, all ht reads precede stores in-block,
// blocks touch only their own rows.
// ---------------------------------------------------------------------------
__global__ void __launch_bounds__(256)
sage_mlp(const unsigned short* ht,            // aliases out!
         const unsigned short* __restrict__ w1sw,
         const unsigned short* __restrict__ w2sw,
         const float* __restrict__ b1,
         const float* __restrict__ b2,
         float* out) {
    __shared__ unsigned short wbuf[16384];      // 32 KB weight staging
    __shared__ unsigned short hid_s[64][264];   // 33.8 KB hidden tile

    const int t = threadIdx.x;
    const int nw = t >> 6;        // wave id = N-slice
    const int lane = t & 63;
    const int lr = lane & 31;
    const int lg = lane >> 5;
    const int base = blockIdx.x * 64;
    const int row0 = min(base + lr,      N_NODES - 1);
    const int row1 = min(base + 32 + lr, N_NODES - 1);

    // ---- Layer 1: hid = A (64x256) @ W1 (256x256) --------------------------
    f32x16 c1[2][2];   // [strip][nt]
    #pragma unroll
    for (int e = 0; e < 16; ++e) {
        c1[0][0][e] = 0.f; c1[0][1][e] = 0.f; c1[1][0][e] = 0.f; c1[1][1][e] = 0.f;
    }

    #pragma unroll
    for (int c = 0; c < 4; ++c) {
        if (c) __syncthreads();               // prior chunk's reads done
        // stage 32 KB W1 chunk (identity copy)
        {
            const bf16x8* gsrc = (const bf16x8*)(w1sw + c * 16384);
            #pragma unroll
            for (int i = 0; i < 8; ++i) {
                int off16 = i * 256 + t;
                *(bf16x8*)(wbuf + off16 * 8) = gsrc[off16];
            }
        }
        // A-frags for this chunk (global, L1-hot: 32 KB of ht rows per block)
        bf16x8 a0[4], a1[4];
        #pragma unroll
        for (int ks = 0; ks < 4; ++ks) {
            int koff = (c * 4 + ks) * 16 + lg * 8;
            a0[ks] = *(const bf16x8*)(ht + (size_t)row0 * 256 + koff);
            a1[ks] = *(const bf16x8*)(ht + (size_t)row1 * 256 + koff);
        }
        __syncthreads();                      // staged chunk visible
        #pragma unroll
        for (int ks = 0; ks < 4; ++ks) {
            #pragma unroll
            for (int nt = 0; nt < 2; ++nt) {
                int n = nw * 64 + nt * 32 + lr;
                bf16x8 b = *(const bf16x8*)(wbuf + (((ks * 2 + lg) * 256) + n) * 8);
                c1[0][nt] = __builtin_amdgcn_mfma_f32_32x32x16_bf16(a0[ks], b, c1[0][nt], 0, 0, 0);
                c1[1][nt] = __builtin_amdgcn_mfma_f32_32x32x16_bf16(a1[ks], b, c1[1][nt], 0, 0, 0);
            }
        }
    }

    // ---- epilogue 1: + b1 -> bf16 -> hid_s (row-major [m][k]) --------------
    #pragma unroll
    for (int nt = 0; nt < 2; ++nt) {
        int col = nw * 64 + nt * 32 + lr;
        float bias = b1[col];
        #pragma unroll
        for (int s = 0; s < 2; ++s) {
            #pragma unroll
            for (int reg = 0; reg < 16; ++reg) {
                int m = s * 32 + (reg & 3) + 8 * (reg >> 2) + 4 * lg;
                hid_s[m][col] = f2bf(c1[s][nt][reg] + bias);
            }
        }
    }
    __syncthreads();    // hid visible + last W1 chunk reads done

    // ---- Layer 2: out = hid (64x256) @ W2 (256x128) ------------------------
    f32x16 c2[2];
    #pragma unroll
    for (int e = 0; e < 16; ++e) { c2[0][e] = 0.f; c2[1][e] = 0.f; }

    #pragma unroll
    for (int c = 0; c < 2; ++c) {
        if (c) __syncthreads();
        {
            const bf16x8* gsrc = (const bf16x8*)(w2sw + c * 16384);
            #pragma unroll
            for (int i = 0; i < 8; ++i) {
                int off16 = i * 256 + t;
                *(bf16x8*)(wbuf + off16 * 8) = gsrc[off16];
            }
        }
        __syncthreads();
        #pragma unroll
        for (int ks = 0; ks < 8; ++ks) {
            bf16x8 b = *(const bf16x8*)(wbuf + ((ks * 2 + lg) * 128 + nw * 32 + lr) * 8);
            int koff = c * 128 + ks * 16 + lg * 8;
            bf16x8 ah0 = *(const bf16x8*)(&hid_s[lr][koff]);
            bf16x8 ah1 = *(const bf16x8*)(&hid_s[32 + lr][koff]);
            c2[0] = __builtin_amdgcn_mfma_f32_32x32x16_bf16(ah0, b, c2[0], 0, 0, 0);
            c2[1] = __builtin_amdgcn_mfma_f32_32x32x16_bf16(ah1, b, c2[1], 0, 0, 0);
        }
    }

    // ---- epilogue 2: + b2, relu, store fp32 --------------------------------
    {
        int col = nw * 32 + lr;
        float bias = b2[col];
        #pragma unroll
        for (int s = 0; s < 2; ++s) {
            #pragma unroll
            for (int reg = 0; reg < 16; ++reg) {
                int m = s * 32 + (reg & 3) + 8 * (reg >> 2) + 4 * lg;
                int n = base + m;
                if (n < N_NODES)
                    out[(size_t)n * OUT_DIM + col] = fmaxf(c2[s][reg] + bias, 0.0f);
            }
        }
    }
}

extern "C" void kernel_launch(void* const* d_in, const int* in_sizes, int n_in,
                              void* d_out, int out_size, void* d_ws, size_t ws_size,
                              hipStream_t stream) {
    const float* h   = (const float*)d_in[0];
    const int*   src = (const int*)d_in[1];
    const int*   dst = (const int*)d_in[2];
    const float* W1  = (const float*)d_in[3];
    const float* b1  = (const float*)d_in[4];
    const float* W2  = (const float*)d_in[5];
    const float* b2  = (const float*)d_in[6];
    float* out = (float*)d_out;

    // ht (bf16 [50000][256] = 25.6 MB) lives in d_out; overwritten by fp32 out.
    unsigned short* ht = (unsigned short*)d_out;

    // ws: counts [50000 int] | bucket [50000*64 int] | w1sw [65536 bf16] | w2sw [32768 bf16]
    int* counts = (int*)d_ws;
    int* bucket = counts + N_NODES;
    unsigned short* w1sw = (unsigned short*)(bucket + (size_t)N_NODES * CAP);
    unsigned short* w2sw = w1sw + 65536;

    hipMemsetAsync(counts, 0, N_NODES * sizeof(int), stream);

    sage_prep<<<NB_FILL + NB_HCVT + NB_WCVT, 256, 0, stream>>>(
        src, dst, counts, bucket, h, ht, W1, W2, w1sw, w2sw);

    sage_gather<<<(N_NODES + 7) / 8, 256, 0, stream>>>(counts, bucket, ht);

    sage_mlp<<<(N_NODES + 63) / 64, 256, 0, stream>>>(ht, w1sw, w2sw, b1, b2, out);
}